// Round 1
// baseline (386.661 us; speedup 1.0000x reference)
//
#include <hip/hip_runtime.h>
#include <cstdint>
#include <cstddef>

// Problem constants (fixed by setup_inputs): B=8, N=4096, C=6, k=16.
#define NPTS   4096
#define NBATCH 8
#define KNN    16
#define INV_DEG (1.0f / 17.0f)

typedef unsigned long long u64;
typedef unsigned int u32;

__device__ __forceinline__ u64 u64min(u64 a, u64 b) { return a < b ? a : b; }
__device__ __forceinline__ u64 u64max(u64 a, u64 b) { return a > b ? a : b; }

// Full 64-lane bitonic sort, ascending by lane. Classic network; __shfl_xor on u64.
__device__ __forceinline__ u64 bitonic64(u64 key, int lane) {
#pragma unroll
  for (int k = 2; k <= 64; k <<= 1) {
#pragma unroll
    for (int m = k >> 1; m >= 1; m >>= 1) {
      u64 partner = __shfl_xor(key, m, 64);
      bool up = ((lane & k) == 0);      // k=64: always ascending (final merge)
      bool lower = ((lane & m) == 0);
      u64 mn = u64min(key, partner);
      u64 mx = u64max(key, partner);
      key = (lower == up) ? mn : mx;
    }
  }
  return key;
}

// ---------------------------------------------------------------------------
// K1: exact KNN (top-16 smallest d2, tie -> lower index), batch-local indices.
// One wave per point (8 points per wave sequentially). grid = 512 blocks x 512.
// blockIdx: b = blk>>6 (batch), 64 points per block.
// d2 computed to mimic numpy: d2 = (sq_i + sq_j) - 2*(x*x' fma y*y' fma z*z')
// with round-to-nearest ops (no unintended contraction).
// ---------------------------------------------------------------------------
__global__ __launch_bounds__(512) void knn_kernel(const float* __restrict__ feats,
                                                  int* __restrict__ nbr) {
  __shared__ float sx[NPTS], sy[NPTS], sz[NPTS];  // 48 KB
  __shared__ u64 sbuf[8 * 128];                   // 8 KB: per-wave candidate buffers

  const int b = blockIdx.x >> 6;
  const int pbase = (blockIdx.x & 63) * 64;
  const float* fb = feats + (size_t)b * NPTS * 6;

  for (int p = threadIdx.x; p < NPTS; p += 512) {
    sx[p] = fb[p * 6 + 0];
    sy[p] = fb[p * 6 + 1];
    sz[p] = fb[p * 6 + 2];
  }
  __syncthreads();

  const int wave = threadIdx.x >> 6;
  const int lane = threadIdx.x & 63;
  u64* wbuf = sbuf + wave * 128;

  for (int pp = 0; pp < 8; ++pp) {
    const int i = pbase + wave * 8 + pp;
    const float xi = sx[i], yi = sy[i], zi = sz[i];
    const float sqi = __fadd_rn(__fadd_rn(__fmul_rn(xi, xi), __fmul_rn(yi, yi)),
                                __fmul_rn(zi, zi));

    u64 slotKey = ~0ull;  // lanes 0..15 hold the current top-16 (sorted after merges)
    u64 tau = ~0ull;      // current 16th-smallest key (uniform), stale-high is safe
    int cnt = 0;

    auto flush = [&]() {
      for (int base0 = 0; base0 < cnt; base0 += 48) {
        u64 key;
        if (lane < 16) {
          key = slotKey;
        } else {
          const int idx = base0 + lane - 16;
          key = (idx < cnt) ? wbuf[idx] : ~0ull;
        }
        key = bitonic64(key, lane);
        if (lane < 16) slotKey = key;
        tau = __shfl(key, 15, 64);
      }
      cnt = 0;
    };

    for (int jb = 0; jb < NPTS; jb += 64) {
      const int j = jb + lane;
      const float xj = sx[j], yj = sy[j], zj = sz[j];
      const float sqj = __fadd_rn(__fadd_rn(__fmul_rn(xj, xj), __fmul_rn(yj, yj)),
                                  __fmul_rn(zj, zj));
      float dot = __fmul_rn(xi, xj);
      dot = __fmaf_rn(yi, yj, dot);
      dot = __fmaf_rn(zi, zj, dot);
      const float d2 = __fsub_rn(__fadd_rn(sqi, sqj), __fmul_rn(2.0f, dot));

      u32 u = __float_as_uint(d2);
      u ^= (u32)((int)u >> 31) | 0x80000000u;  // monotonic map (handles tiny negatives)
      u64 key = ((u64)u << 32) | (u32)j;
      if (j == i) key = ~0ull;                 // exclude self

      const bool pred = key < tau;             // strict <: tie -> already-held lower idx wins
      const u64 bal = __ballot(pred);
      if (bal) {
        const int npass = __popcll(bal);
        if (cnt + npass > 128) flush();        // capacity-safe (npass <= 64)
        const int pos = cnt + __popcll(bal & ((1ull << lane) - 1ull));
        if (pred) wbuf[pos] = key;
        cnt += npass;
      }
    }
    flush();  // final merge; slots = 16 smallest, ascending by distance

    if (lane < KNN)
      nbr[((size_t)(b * NPTS + i)) * KNN + lane] = (int)(slotKey & 0xFFFFFFFFu);
  }
}

// ---------------------------------------------------------------------------
// K2: h1 = feats @ W1   (per-thread (n,c), c<64). grid 8192 x 256.
// ---------------------------------------------------------------------------
__global__ __launch_bounds__(256) void mlp1_kernel(const float* __restrict__ feats,
                                                   const float* __restrict__ W1,
                                                   float* __restrict__ h1) {
  const int c = threadIdx.x & 63;
  const int n = blockIdx.x * 4 + (threadIdx.x >> 6);
  const float* f = feats + (size_t)n * 6;
  float s = 0.f;
#pragma unroll
  for (int k = 0; k < 6; ++k) s = fmaf(f[k], W1[k * 64 + c], s);
  h1[(size_t)n * 64 + c] = s;
}

// ---------------------------------------------------------------------------
// K3: x1 = relu((sum_nbr h1 + h1) * inv_deg + b1), C=64. grid 8192 x 256.
// ---------------------------------------------------------------------------
__global__ __launch_bounds__(256) void agg1_kernel(const float* __restrict__ h1,
                                                   const int* __restrict__ nbr,
                                                   const float* __restrict__ b1,
                                                   float* __restrict__ x1) {
  const int c = threadIdx.x & 63;
  const int n = blockIdx.x * 4 + (threadIdx.x >> 6);
  const int* nb = nbr + (size_t)n * KNN;
  const int gb = n & ~(NPTS - 1);  // batch base row
  float s = h1[(size_t)n * 64 + c];
#pragma unroll
  for (int t = 0; t < KNN; ++t) s += h1[(size_t)(gb + nb[t]) * 64 + c];
  x1[(size_t)n * 64 + c] = fmaxf(fmaf(s, INV_DEG, b1[c]), 0.f);
}

// ---------------------------------------------------------------------------
// K4: h2 = x1 @ W2  (K=64 -> C=128). W2 column in 64 VGPRs, row broadcast via
// v_readlane (no LDS pipe). Block 256 = 2 point-groups x 128 c; 32 pts/block.
// ---------------------------------------------------------------------------
__global__ __launch_bounds__(256) void mlp2_kernel(const float* __restrict__ x1,
                                                   const float* __restrict__ W2,
                                                   float* __restrict__ h2) {
  const int tid = threadIdx.x;
  const int c = tid & 127;
  const int half = tid >> 7;
  const int lane = tid & 63;

  float w[64];
#pragma unroll
  for (int k = 0; k < 64; ++k) w[k] = W2[k * 128 + c];

  const int nbase = blockIdx.x * 32 + half * 16;
  for (int it = 0; it < 16; ++it) {
    const int n = nbase + it;
    const float xr = x1[(size_t)n * 64 + lane];
    const int xri = __float_as_int(xr);
    float s0 = 0.f, s1 = 0.f, s2 = 0.f, s3 = 0.f;
#pragma unroll
    for (int k = 0; k < 64; k += 4) {
      s0 = fmaf(__int_as_float(__builtin_amdgcn_readlane(xri, k + 0)), w[k + 0], s0);
      s1 = fmaf(__int_as_float(__builtin_amdgcn_readlane(xri, k + 1)), w[k + 1], s1);
      s2 = fmaf(__int_as_float(__builtin_amdgcn_readlane(xri, k + 2)), w[k + 2], s2);
      s3 = fmaf(__int_as_float(__builtin_amdgcn_readlane(xri, k + 3)), w[k + 3], s3);
    }
    h2[(size_t)n * 128 + c] = (s0 + s1) + (s2 + s3);
  }
}

// ---------------------------------------------------------------------------
// K5: x2 = relu((sum_nbr h2 + h2) * inv_deg + b2), C=128. grid 16384 x 256.
// ---------------------------------------------------------------------------
__global__ __launch_bounds__(256) void agg2_kernel(const float* __restrict__ h2,
                                                   const int* __restrict__ nbr,
                                                   const float* __restrict__ b2,
                                                   float* __restrict__ x2) {
  const int c = threadIdx.x & 127;
  const int n = blockIdx.x * 2 + (threadIdx.x >> 7);
  const int* nb = nbr + (size_t)n * KNN;
  const int gb = n & ~(NPTS - 1);
  float s = h2[(size_t)n * 128 + c];
#pragma unroll
  for (int t = 0; t < KNN; ++t) s += h2[(size_t)(gb + nb[t]) * 128 + c];
  x2[(size_t)n * 128 + c] = fmaxf(fmaf(s, INV_DEG, b2[c]), 0.f);
}

// ---------------------------------------------------------------------------
// K6: out = x2 @ Wf + bf  (K=128 -> C=128). Split-K across two thread halves,
// combine via LDS. Block 256 = 128 c x 2 k-halves; 16 pts/block.
// ---------------------------------------------------------------------------
__global__ __launch_bounds__(256) void mlp3_kernel(const float* __restrict__ x2,
                                                   const float* __restrict__ Wf,
                                                   const float* __restrict__ bf,
                                                   float* __restrict__ out) {
  __shared__ float part[256];
  const int tid = threadIdx.x;
  const int c = tid & 127;
  const int kh = tid >> 7;
  const int lane = tid & 63;

  float w[64];
#pragma unroll
  for (int j = 0; j < 64; ++j) w[j] = Wf[(size_t)(kh * 64 + j) * 128 + c];

  const float bv = bf[c];
  const int nbase = blockIdx.x * 16;
  for (int it = 0; it < 16; ++it) {
    const int n = nbase + it;
    const float xr = x2[(size_t)n * 128 + kh * 64 + lane];
    const int xri = __float_as_int(xr);
    float s0 = 0.f, s1 = 0.f, s2 = 0.f, s3 = 0.f;
#pragma unroll
    for (int j = 0; j < 64; j += 4) {
      s0 = fmaf(__int_as_float(__builtin_amdgcn_readlane(xri, j + 0)), w[j + 0], s0);
      s1 = fmaf(__int_as_float(__builtin_amdgcn_readlane(xri, j + 1)), w[j + 1], s1);
      s2 = fmaf(__int_as_float(__builtin_amdgcn_readlane(xri, j + 2)), w[j + 2], s2);
      s3 = fmaf(__int_as_float(__builtin_amdgcn_readlane(xri, j + 3)), w[j + 3], s3);
    }
    const float s = (s0 + s1) + (s2 + s3);
    part[tid] = s;
    __syncthreads();
    if (kh == 0) out[(size_t)n * 128 + c] = s + part[tid + 128] + bv;
    __syncthreads();
  }
}

// ---------------------------------------------------------------------------
// Workspace layout (needs 34 MB):
//   [0,2MB)    nbr  : int[8*4096*16]
//   [2,10MB)   h1   : float[8*4096*64]
//   [10,18MB)  x1   : float[8*4096*64]
//   [18,34MB)  x2   : float[8*4096*128]
// h2 lives in d_out (same size as output), overwritten by the final GEMM.
// ---------------------------------------------------------------------------
extern "C" void kernel_launch(void* const* d_in, const int* in_sizes, int n_in,
                              void* d_out, int out_size, void* d_ws, size_t ws_size,
                              hipStream_t stream) {
  const float* feats = (const float*)d_in[0];
  const float* W1 = (const float*)d_in[1];
  const float* b1 = (const float*)d_in[2];
  const float* W2 = (const float*)d_in[3];
  const float* b2 = (const float*)d_in[4];
  const float* Wf = (const float*)d_in[5];
  const float* bf = (const float*)d_in[6];
  float* out = (float*)d_out;

  char* ws = (char*)d_ws;
  int* nbr = (int*)ws;
  float* h1 = (float*)(ws + (size_t)(2 << 20));
  float* x1 = (float*)(ws + (size_t)(10 << 20));
  float* x2 = (float*)(ws + (size_t)(18 << 20));
  float* h2 = out;  // reuse output buffer for the layer-2 pre-aggregation

  knn_kernel<<<512, 512, 0, stream>>>(feats, nbr);
  mlp1_kernel<<<8192, 256, 0, stream>>>(feats, W1, h1);
  agg1_kernel<<<8192, 256, 0, stream>>>(h1, nbr, b1, x1);
  mlp2_kernel<<<1024, 256, 0, stream>>>(x1, W2, h2);
  agg2_kernel<<<16384, 256, 0, stream>>>(h2, nbr, b2, x2);
  mlp3_kernel<<<2048, 256, 0, stream>>>(x2, Wf, bf, out);
}

// Round 2
// 277.926 us; speedup vs baseline: 1.3912x; 1.3912x over previous
//
#include <hip/hip_runtime.h>
#include <cstdint>
#include <cstddef>

#define NPTS 4096
#define KNN  16
#define INV_DEG (1.0f / 17.0f)
#define CAP 48   // knn buffer capacity; entries [48..64) = slot staging region

typedef unsigned long long u64;
typedef unsigned int u32;
typedef float v2f __attribute__((ext_vector_type(2)));

__device__ __forceinline__ u32 mapmono(float f) {
  u32 u = __float_as_uint(f);
  return u ^ ((u32)((int)u >> 31) | 0x80000000u);
}
__device__ __forceinline__ float unmapmono(u32 m) {
  u32 u = (m & 0x80000000u) ? (m ^ 0x80000000u) : ~m;
  return __uint_as_float(u);
}

// ---------------------------------------------------------------------------
// K1: exact KNN. One wave handles 4 points concurrently (x2 groups = 8/wave).
// Hot loop: float-threshold filter only; key build + selection in rare path.
// Selection = LDS rank-select over {<=48 buffered} U {16 slots}; ties broken
// by index via monotonic-u64 keys (matches top_k first-occurrence order).
// ---------------------------------------------------------------------------
__global__ __launch_bounds__(512) void knn_kernel(const float* __restrict__ feats,
                                                  int* __restrict__ nbr) {
#pragma clang fp contract(off)
  __shared__ float sx[NPTS], sy[NPTS], sz[NPTS];  // 48 KB
  __shared__ u64 sbuf[8][4][64];                  // 16 KB

  const int b = blockIdx.x >> 6;
  const int pbase = (blockIdx.x & 63) * 64;
  const float* fb = feats + (size_t)b * NPTS * 6;

  for (int p = threadIdx.x; p < NPTS; p += 512) {
    sx[p] = fb[p * 6 + 0];
    sy[p] = fb[p * 6 + 1];
    sz[p] = fb[p * 6 + 2];
  }
  __syncthreads();

  const int wave = threadIdx.x >> 6;
  const int lane = threadIdx.x & 63;

  for (int g = 0; g < 2; ++g) {
    int ip[4];
    float xi[4], yi[4], zi[4], sqi[4], tau[4];
    u64 slot[4];
    int cnt[4];
#pragma unroll
    for (int p = 0; p < 4; ++p) {
      ip[p] = pbase + wave * 8 + g * 4 + p;
      xi[p] = sx[ip[p]]; yi[p] = sy[ip[p]]; zi[p] = sz[ip[p]];
      sqi[p] = __fadd_rn(__fadd_rn(__fmul_rn(xi[p], xi[p]), __fmul_rn(yi[p], yi[p])),
                         __fmul_rn(zi[p], zi[p]));
      tau[p] = __uint_as_float(0x7f800000u);  // +inf
      slot[p] = ~0ull;
      cnt[p] = 0;
    }

    // stage=false: buffer holds 64 raw keys (batch-0 bootstrap).
    // fin=true: write nbr[rank] directly instead of updating slots.
    auto flushN = [&](int p, bool stage, bool fin) {
      u64* wb = &sbuf[wave][p][0];
      if (stage) {
        if (lane >= cnt[p] && lane < CAP) wb[lane] = ~0ull;  // clear unused
        if (lane < KNN) wb[CAP + lane] = slot[p];            // stage slots
      }
      u64 myk = wb[lane];
      if ((u32)myk == (u32)ip[p]) {  // neutralize self (sentinel low32 != ip)
        myk = ~0ull;
        wb[lane] = ~0ull;
      }
      int rank = 0;
#pragma unroll
      for (int m = 0; m < 64; m += 4) {
        u64 k0 = wb[m], k1 = wb[m + 1], k2 = wb[m + 2], k3 = wb[m + 3];
        rank += (int)(k0 < myk) + (int)(k1 < myk) + (int)(k2 < myk) + (int)(k3 < myk);
      }
      if (fin) {
        if (rank < KNN)
          nbr[((size_t)(b * NPTS) + ip[p]) * KNN + rank] = (int)(u32)myk;
      } else {
        if (rank < KNN) wb[rank] = myk;
        u64 s15 = wb[15];
        if (lane < KNN) slot[p] = wb[lane];
        tau[p] = unmapmono((u32)(s15 >> 32));
      }
      cnt[p] = 0;
    };

    // ---- batch 0: all candidates pass (tau=inf); bootstrap slots+tau ----
    {
      const float cx = sx[lane], cy = sy[lane], cz = sz[lane];
      const float sqj = __fadd_rn(__fadd_rn(__fmul_rn(cx, cx), __fmul_rn(cy, cy)),
                                  __fmul_rn(cz, cz));
#pragma unroll
      for (int p = 0; p < 4; ++p) {
        float dot = __fmul_rn(xi[p], cx);
        dot = __fmaf_rn(yi[p], cy, dot);
        dot = __fmaf_rn(zi[p], cz, dot);
        float d2 = __fsub_rn(__fadd_rn(sqi[p], sqj), __fmul_rn(2.0f, dot));
        sbuf[wave][p][lane] = ((u64)mapmono(d2) << 32) | (u32)lane;
        flushN(p, false, false);
      }
    }

    // ---- batches 1..63: packed-fp32 scan, rare-path buffering ----
    for (int jb = 64; jb < NPTS; jb += 64) {
      const int j = jb + lane;
      const float cx = sx[j], cy = sy[j], cz = sz[j];
      const float sqj = __fadd_rn(__fadd_rn(__fmul_rn(cx, cx), __fmul_rn(cy, cy)),
                                  __fmul_rn(cz, cz));
      const v2f cx2 = {cx, cx}, cy2 = {cy, cy}, cz2 = {cz, cz}, sq2 = {sqj, sqj};
      float d2s[4];
#pragma unroll
      for (int pp = 0; pp < 2; ++pp) {
        v2f X = {xi[2 * pp], xi[2 * pp + 1]};
        v2f Y = {yi[2 * pp], yi[2 * pp + 1]};
        v2f Z = {zi[2 * pp], zi[2 * pp + 1]};
        v2f SQ = {sqi[2 * pp], sqi[2 * pp + 1]};
        v2f dot = X * cx2;
        dot = __builtin_elementwise_fma(Y, cy2, dot);
        dot = __builtin_elementwise_fma(Z, cz2, dot);
        v2f two = {2.0f, 2.0f};
        v2f d2 = (SQ + sq2) - two * dot;  // contract(off): add, mul, sub — rn each
        d2s[2 * pp] = d2.x;
        d2s[2 * pp + 1] = d2.y;
      }
#pragma unroll
      for (int p = 0; p < 4; ++p) {
        const bool pred = d2s[p] <= tau[p];
        const u64 bal = __ballot(pred);
        if (bal) {
          const int npass = __popcll(bal);
          if (cnt[p] + npass > CAP) flushN(p, true, false);
          const int pos = cnt[p] + (int)__builtin_amdgcn_mbcnt_hi(
                                        (u32)(bal >> 32),
                                        __builtin_amdgcn_mbcnt_lo((u32)bal, 0));
          const u64 key = ((u64)mapmono(d2s[p]) << 32) | (u32)j;
          if (npass <= CAP) {
            if (pred) sbuf[wave][p][pos] = key;
            cnt[p] += npass;
          } else {  // pathological ties: npass in (48,64]; split across 2 flushes
            if (pred && pos < CAP) sbuf[wave][p][pos] = key;
            cnt[p] = CAP;
            flushN(p, true, false);
            if (pred && pos >= CAP) sbuf[wave][p][pos - CAP] = key;
            cnt[p] = npass - CAP;
          }
        }
      }
    }

#pragma unroll
    for (int p = 0; p < 4; ++p) flushN(p, true, true);
  }
}

// ---------------------------------------------------------------------------
// K2: afeats[n] = feats[n] + sum_nbr feats  (C=6). One thread per point.
// ---------------------------------------------------------------------------
__global__ __launch_bounds__(256) void aggf_kernel(const float* __restrict__ feats,
                                                   const int* __restrict__ nbr,
                                                   float* __restrict__ af) {
  const int n = blockIdx.x * 256 + threadIdx.x;
  const int gb = n & ~(NPTS - 1);
  const int* nb = nbr + (size_t)n * KNN;
  const float* f0 = feats + (size_t)n * 6;
  float a0 = f0[0], a1 = f0[1], a2 = f0[2], a3 = f0[3], a4 = f0[4], a5 = f0[5];
#pragma unroll
  for (int t = 0; t < KNN; ++t) {
    const float* fr = feats + (size_t)(gb + nb[t]) * 6;
    a0 += fr[0]; a1 += fr[1]; a2 += fr[2];
    a3 += fr[3]; a4 += fr[4]; a5 += fr[5];
  }
  float* o = af + (size_t)n * 6;
  o[0] = a0; o[1] = a1; o[2] = a2; o[3] = a3; o[4] = a4; o[5] = a5;
}

// ---------------------------------------------------------------------------
// K3: x1 = relu((af @ W1) * inv_deg + b1), 6 -> 64.
// ---------------------------------------------------------------------------
__global__ __launch_bounds__(256) void gemm1_kernel(const float* __restrict__ af,
                                                    const float* __restrict__ W1,
                                                    const float* __restrict__ b1,
                                                    float* __restrict__ x1) {
  const int c = threadIdx.x & 63;
  const int n = blockIdx.x * 4 + (threadIdx.x >> 6);
  const float* a = af + (size_t)n * 6;
  float s = 0.f;
#pragma unroll
  for (int k = 0; k < 6; ++k) s = fmaf(a[k], W1[k * 64 + c], s);
  x1[(size_t)n * 64 + c] = fmaxf(fmaf(s, INV_DEG, b1[c]), 0.f);
}

// ---------------------------------------------------------------------------
// K4: a1[n] = x1[n] + sum_nbr x1  (C=64), float4 per thread (16 thr/point).
// ---------------------------------------------------------------------------
__global__ __launch_bounds__(256) void aggx_kernel(const float* __restrict__ x1,
                                                   const int* __restrict__ nbr,
                                                   float* __restrict__ a1) {
  const int t16 = threadIdx.x & 15;
  const int n = blockIdx.x * 16 + (threadIdx.x >> 4);
  const int gb = n & ~(NPTS - 1);
  const int* nb = nbr + (size_t)n * KNN;
  float4 s = ((const float4*)(x1 + (size_t)n * 64))[t16];
#pragma unroll
  for (int t = 0; t < KNN; ++t) {
    float4 v = ((const float4*)(x1 + (size_t)(gb + nb[t]) * 64))[t16];
    s.x += v.x; s.y += v.y; s.z += v.z; s.w += v.w;
  }
  ((float4*)(a1 + (size_t)n * 64))[t16] = s;
}

// ---------------------------------------------------------------------------
// K5: x2 = relu((a1 @ W2) * inv_deg + b2), 64 -> 128. W col in VGPRs,
// row broadcast via readlane.
// ---------------------------------------------------------------------------
__global__ __launch_bounds__(256) void gemm2_kernel(const float* __restrict__ a1,
                                                    const float* __restrict__ W2,
                                                    const float* __restrict__ b2,
                                                    float* __restrict__ x2) {
  const int tid = threadIdx.x;
  const int c = tid & 127;
  const int half = tid >> 7;
  const int lane = tid & 63;

  float w[64];
#pragma unroll
  for (int k = 0; k < 64; ++k) w[k] = W2[k * 128 + c];
  const float bv = b2[c];

  const int nbase = blockIdx.x * 32 + half * 16;
  for (int it = 0; it < 16; ++it) {
    const int n = nbase + it;
    const float xr = a1[(size_t)n * 64 + lane];
    const int xri = __float_as_int(xr);
    float s0 = 0.f, s1 = 0.f, s2 = 0.f, s3 = 0.f;
#pragma unroll
    for (int k = 0; k < 64; k += 4) {
      s0 = fmaf(__int_as_float(__builtin_amdgcn_readlane(xri, k + 0)), w[k + 0], s0);
      s1 = fmaf(__int_as_float(__builtin_amdgcn_readlane(xri, k + 1)), w[k + 1], s1);
      s2 = fmaf(__int_as_float(__builtin_amdgcn_readlane(xri, k + 2)), w[k + 2], s2);
      s3 = fmaf(__int_as_float(__builtin_amdgcn_readlane(xri, k + 3)), w[k + 3], s3);
    }
    const float s = (s0 + s1) + (s2 + s3);
    x2[(size_t)n * 128 + c] = fmaxf(fmaf(s, INV_DEG, bv), 0.f);
  }
}

// ---------------------------------------------------------------------------
// K6: out = x2 @ Wf + bf, 128 -> 128. Split-K halves, LDS combine.
// In-place safe on d_out: each row read (pre-barrier) before written.
// ---------------------------------------------------------------------------
__global__ __launch_bounds__(256) void gemm3_kernel(const float* __restrict__ x2,
                                                    const float* __restrict__ Wf,
                                                    const float* __restrict__ bf,
                                                    float* __restrict__ out) {
  __shared__ float part[256];
  const int tid = threadIdx.x;
  const int c = tid & 127;
  const int kh = tid >> 7;
  const int lane = tid & 63;

  float w[64];
#pragma unroll
  for (int j = 0; j < 64; ++j) w[j] = Wf[(size_t)(kh * 64 + j) * 128 + c];
  const float bv = bf[c];

  const int nbase = blockIdx.x * 16;
  for (int it = 0; it < 16; ++it) {
    const int n = nbase + it;
    const float xr = x2[(size_t)n * 128 + kh * 64 + lane];
    const int xri = __float_as_int(xr);
    float s0 = 0.f, s1 = 0.f, s2 = 0.f, s3 = 0.f;
#pragma unroll
    for (int j = 0; j < 64; j += 4) {
      s0 = fmaf(__int_as_float(__builtin_amdgcn_readlane(xri, j + 0)), w[j + 0], s0);
      s1 = fmaf(__int_as_float(__builtin_amdgcn_readlane(xri, j + 1)), w[j + 1], s1);
      s2 = fmaf(__int_as_float(__builtin_amdgcn_readlane(xri, j + 2)), w[j + 2], s2);
      s3 = fmaf(__int_as_float(__builtin_amdgcn_readlane(xri, j + 3)), w[j + 3], s3);
    }
    const float s = (s0 + s1) + (s2 + s3);
    part[tid] = s;
    __syncthreads();
    if (kh == 0) out[(size_t)n * 128 + c] = s + part[tid + 128] + bv;
    __syncthreads();
  }
}

// ---------------------------------------------------------------------------
// Workspace: nbr@0 (2MB), af@2MB (0.75MB), x1@3MB (8MB), a1@11MB (8MB).
// x2 lives in d_out (overwritten in place by gemm3 — safe, see K6).
// ---------------------------------------------------------------------------
extern "C" void kernel_launch(void* const* d_in, const int* in_sizes, int n_in,
                              void* d_out, int out_size, void* d_ws, size_t ws_size,
                              hipStream_t stream) {
  const float* feats = (const float*)d_in[0];
  const float* W1 = (const float*)d_in[1];
  const float* b1 = (const float*)d_in[2];
  const float* W2 = (const float*)d_in[3];
  const float* b2 = (const float*)d_in[4];
  const float* Wf = (const float*)d_in[5];
  const float* bf = (const float*)d_in[6];
  float* out = (float*)d_out;

  char* ws = (char*)d_ws;
  int* nbr = (int*)ws;
  float* af = (float*)(ws + (size_t)(2 << 20));
  float* x1 = (float*)(ws + (size_t)(3 << 20));
  float* a1 = (float*)(ws + (size_t)(11 << 20));
  float* x2 = out;

  knn_kernel<<<512, 512, 0, stream>>>(feats, nbr);
  aggf_kernel<<<128, 256, 0, stream>>>(feats, nbr, af);
  gemm1_kernel<<<8192, 256, 0, stream>>>(af, W1, b1, x1);
  aggx_kernel<<<2048, 256, 0, stream>>>(x1, nbr, a1);
  gemm2_kernel<<<1024, 256, 0, stream>>>(a1, W2, b2, x2);
  gemm3_kernel<<<2048, 256, 0, stream>>>(x2, Wf, bf, out);
}